// Round 1
// baseline (273.083 us; speedup 1.0000x reference)
//
#include <hip/hip_runtime.h>

// R9: identical to R8 (reverse-order tiles, LDS-staged float2 path) except the
// output stores are NON-TEMPORAL (global_store_dwordx2 nt).
// Theory: in-situ kernel window is 96 us for 266 MB (2.8 TB/s) while the
// immediately-preceding fill sustains 6.6 TB/s -- the window is not HBM-bound.
// Blame: write-ALLOCATING stores must insert lines into the same L2/MALL sets
// the drain engine is walking to flush the ~1 GB poison fill; each store pays
// allocate+displace serialized against the drain. nt = no-allocate/evict-first:
// misses stream past the drain front, hits still overwrite dirty poison in
// place (keeps R8's drain-cancellation).
// Predict: dur_us 248 -> ~205-215 if right; ~255-270 if nt loses cancellation.

constexpr int N_CONTEXT = 9;
constexpr int C         = 26;                 // N_INPUT
constexpr int WINDOW    = 2 * N_CONTEXT + 1;  // 19
constexpr int BATCH     = 64;
constexpr int TIME      = 2000;
constexpr int ROW       = WINDOW * C;         // 494 floats per output row
constexpr int ROW2      = ROW / 2;            // 247 float2 columns per row
constexpr int C2        = C / 2;              // 13 float2 per time step

constexpr int T_TILE    = 40;                    // 40 | 2000 -> batch-uniform tiles
constexpr int LDS_ROWS  = T_TILE + WINDOW - 1;   // 58 time steps staged
constexpr int LDS_F2    = LDS_ROWS * C2;         // 754 float2 (6 KB)
constexpr int BLOCK     = 256;
constexpr int NBLOCKS   = BATCH * TIME / T_TILE; // 3200
constexpr int BATCH_F2  = TIME * C2;             // 26000 float2 per batch

typedef float f32x2 __attribute__((ext_vector_type(2)));

__global__ __launch_bounds__(BLOCK)
void CreateOverlappingWindows_84963043050043_kernel(const float* __restrict__ x,
                                                    float* __restrict__ out) {
    __shared__ f32x2 lds2[LDS_F2];
    const int tid  = threadIdx.x;
    const int tile = (NBLOCKS - 1) - blockIdx.x;   // REVERSE dispatch order
    const int r0   = tile * T_TILE;          // first output row of tile
    const int b    = r0 / TIME;              // batch (tile is batch-uniform)
    const int lo2  = b * BATCH_F2;           // valid float2 range for batch
    const int base2 = ((r0 - N_CONTEXT) * C) >> 1;
    const f32x2* x2 = reinterpret_cast<const f32x2*>(x);

    // Phase 1: stage x[b, r0-9 .. r0+39+9, :] as float2; zeros materialized at
    // batch edges (single unsigned range check, boundaries float2-aligned).
    #pragma unroll
    for (int it = 0; it < (LDS_F2 + BLOCK - 1) / BLOCK; ++it) {
        int idx = tid + it * BLOCK;
        if (idx < LDS_F2) {
            int g = base2 + idx;
            f32x2 v = {0.0f, 0.0f};
            if ((unsigned)(g - lo2) < (unsigned)BATCH_F2) v = x2[g];
            lds2[idx] = v;
        }
    }
    __syncthreads();

    // Phase 2: thread = column pair, loop = rows. One ds_read_b64 + one
    // independent NON-TEMPORAL global_store_dwordx2 per row; no index math.
    if (tid < ROW2) {
        f32x2* o2 = reinterpret_cast<f32x2*>(out) + (size_t)r0 * ROW2 + tid;
        #pragma unroll
        for (int lt = 0; lt < T_TILE; ++lt) {
            __builtin_nontemporal_store(lds2[lt * C2 + tid], &o2[(size_t)lt * ROW2]);
        }
    }
}

extern "C" void kernel_launch(void* const* d_in, const int* in_sizes, int n_in,
                              void* d_out, int out_size, void* d_ws, size_t ws_size,
                              hipStream_t stream) {
    const float* x = (const float*)d_in[0];
    float* out = (float*)d_out;
    CreateOverlappingWindows_84963043050043_kernel<<<NBLOCKS, BLOCK, 0, stream>>>(x, out);
}